// Round 2
// baseline (591.544 us; speedup 1.0000x reference)
//
#include <hip/hip_runtime.h>
#include <hip/hip_bf16.h>

// Problem constants
#define BB 16
#define CC 64
#define HH 64
#define WW 64
#define QQ 8192
#define HID 256
#define KK 576            // C*9
#define HT 66             // H + 2 halo
#define FROW 264          // 257 channels padded to 264 (16B-aligned rows)

typedef short short8 __attribute__((ext_vector_type(8)));
typedef float f32x4 __attribute__((ext_vector_type(4)));

__device__ __forceinline__ short f2bf(float f) {
    union { float f; unsigned u; } v; v.f = f;
    unsigned r = v.u + 0x7fffu + ((v.u >> 16) & 1u);
    return (short)(r >> 16);
}
__device__ __forceinline__ float bf2f(short s) {
    union { unsigned u; float f; } v; v.u = ((unsigned)(unsigned short)s) << 16;
    return v.f;
}

// ---------------------------------------------------------------------------
// Kernel P: repack weights to bf16.
//   w3convT[n][kk], kk = pos*64 + c :  = w3[n][c*9+pos] (n<256), b3[c*9+pos] (n==256), 0 pad
//   w2bT[n][k] = w2[k][n]
// ---------------------------------------------------------------------------
__global__ __launch_bounds__(256) void prep_k(const float* __restrict__ w2,
                                              const float* __restrict__ w3,
                                              const float* __restrict__ b3,
                                              short* __restrict__ w3cT,
                                              short* __restrict__ w2bT) {
    int stride = gridDim.x * blockDim.x;
    for (int idx = blockIdx.x * blockDim.x + threadIdx.x; idx < 272 * KK; idx += stride) {
        int n = idx / KK, kk = idx - n * KK;
        int pos = kk >> 6, c = kk & 63;
        float v = 0.f;
        if (n < 256)      v = w3[n * KK + c * 9 + pos];
        else if (n == 256) v = b3[c * 9 + pos];
        w3cT[idx] = f2bf(v);
    }
    for (int idx = blockIdx.x * blockDim.x + threadIdx.x; idx < 256 * 256; idx += stride) {
        int n = idx >> 8, k = idx & 255;
        w2bT[idx] = f2bf(w2[k * 256 + n]);
    }
}

// ---------------------------------------------------------------------------
// Kernel T: feat [b][c][y][x] f32  ->  featT [b][yy][xx][c] bf16 with zero halo
// ---------------------------------------------------------------------------
__global__ __launch_bounds__(256) void transpose_k(const float* __restrict__ feat,
                                                   short* __restrict__ featT) {
    __shared__ float ftile[64][65];
    const int t = threadIdx.x;
    const int b = blockIdx.x / HT;
    const int yy = blockIdx.x - b * HT;
    short* out_row = featT + ((b * HT + yy) * HT) * 64;   // plane of HT*64 shorts

    if (yy == 0 || yy == HT - 1) {
        for (int idx = t; idx < HT * 64; idx += 256) out_row[idx] = 0;
        return;
    }
    const int y = yy - 1;
    const float* src = feat + ((b * CC) * HH + y) * WW;   // + c*HH*WW + x
#pragma unroll
    for (int i = 0; i < 16; ++i) {
        int idx = i * 256 + t;
        int c = idx >> 6, x = idx & 63;
        ftile[c][x] = src[c * (HH * WW) + x];
    }
    // halo columns (xx=0 and xx=65)
    if (t < 64) out_row[t] = 0;
    else if (t < 128) out_row[(HT - 1) * 64 + (t - 64)] = 0;
    __syncthreads();
#pragma unroll
    for (int i = 0; i < 16; ++i) {
        int idx = i * 256 + t;
        int x = idx >> 6, c = idx & 63;
        out_row[(x + 1) * 64 + c] = f2bf(ftile[c][x]);
    }
}

// ---------------------------------------------------------------------------
// Kernel C: conv as implicit GEMM.  F[b,y,x,n] = sum_k A[pixel,k]*w3convT[n,k]
//   wg = (b,y): M=64 pixels, N=272 (wave0 takes the extra subtile), K=576
//   Epilogue stages C through LDS (union with A-tile) for full-line stores.
// ---------------------------------------------------------------------------
#define ALDS_STRIDE 72   // 64 kk + 8 pad (144B rows, 16B-aligned)
__global__ __launch_bounds__(256) void conv_k(const short* __restrict__ featT,
                                              const short* __restrict__ w3cT,
                                              short* __restrict__ F) {
    // union: first 64*72 shorts = A-tile during k-loop; whole = 64x264 C-tile in epilogue
    __shared__ short lds[64 * FROW];     // 33,792 B
    short* A_lds = lds;
    const int t = threadIdx.x;
    const int wave = t >> 6, lane = t & 63, quad = lane >> 4, ln16 = lane & 15;
    const int b = blockIdx.x >> 6, y = blockIdx.x & 63;
    const int nsub = (wave == 0) ? 5 : 4;

    f32x4 acc[4][5];
#pragma unroll
    for (int a = 0; a < 4; ++a)
#pragma unroll
        for (int i = 0; i < 5; ++i) acc[a][i] = (f32x4){0.f, 0.f, 0.f, 0.f};

    const short* featb = featT + b * (HT * HT * 64);

    for (int pos = 0; pos < 9; ++pos) {
        const int di = pos / 3;
        const int dj = pos - di * 3;
        const short* srcbase = featb + ((y + di) * HT + dj) * 64;  // + m*64 + c

        // Preload B fragments for this pos (global/L2; no LDS dependency, so
        // their latency overlaps the A-staging below).
        short8 bfr[2][5];
        for (int ks = 0; ks < 2; ++ks)
            for (int i = 0; i < nsub; ++i) {
                int sub = (i < 4) ? (wave + 4 * i) : 16;
                int n = sub * 16 + ln16;
                bfr[ks][i] = *(const short8*)(w3cT + n * KK + pos * 64 + ks * 32 + quad * 8);
            }

        __syncthreads();   // previous iteration's A-frag reads complete
#pragma unroll
        for (int i = 0; i < 2; ++i) {
            int idx = i * 256 + t;          // 0..511 -> 64 rows x 8 segs
            int m = idx >> 3;
            int cs = (idx & 7) * 8;
            short8 v = *(const short8*)(srcbase + m * 64 + cs);
            *(short8*)(&A_lds[m * ALDS_STRIDE + cs]) = v;
        }
        __syncthreads();

#pragma unroll
        for (int ks = 0; ks < 2; ++ks) {
            short8 af[4];
#pragma unroll
            for (int ms = 0; ms < 4; ++ms)
                af[ms] = *(const short8*)(&A_lds[(ms * 16 + ln16) * ALDS_STRIDE + ks * 32 + quad * 8]);
            for (int i = 0; i < nsub; ++i) {
#pragma unroll
                for (int ms = 0; ms < 4; ++ms)
                    acc[ms][i] = __builtin_amdgcn_mfma_f32_16x16x32_bf16(af[ms], bfr[ks][i], acc[ms][i], 0, 0, 0);
            }
        }
    }

    __syncthreads();   // all A-tile reads done; reuse lds as C-tile
    // Scatter accumulator into C_lds[x][n]
    for (int i = 0; i < nsub; ++i) {
        int sub = (i < 4) ? (wave + 4 * i) : 16;
        int n = sub * 16 + ln16;
        if (n < FROW) {
#pragma unroll
            for (int ms = 0; ms < 4; ++ms)
#pragma unroll
                for (int r = 0; r < 4; ++r) {
                    int x = ms * 16 + quad * 4 + r;
                    lds[x * FROW + n] = f2bf(acc[ms][i][r]);
                }
        }
    }
    __syncthreads();
    // Flat vectorized copy: LDS C-tile -> F (full-line coalesced stores)
    short8* dst = (short8*)(F + (long)(b * 64 + y) * 64 * FROW);
    const short8* src8 = (const short8*)lds;
    for (int idx = t; idx < (64 * FROW) / 8; idx += 256)
        dst[idx] = src8[idx];
}

// ---------------------------------------------------------------------------
// Kernel M: per-64-query tile: coords -> inp -> H1 (VALU) -> H2 (MFMA) ->
//           dot with gathered F row.
// ---------------------------------------------------------------------------
#define HSTRIDE 264
__global__ __launch_bounds__(256) void mlp_k(const float* __restrict__ coord,
                                             const float* __restrict__ cell,
                                             const float* __restrict__ w1,
                                             const float* __restrict__ b1,
                                             const float* __restrict__ b2v,
                                             const short* __restrict__ w2bT,
                                             const short* __restrict__ F,
                                             float* __restrict__ out) {
    __shared__ float inp_s[64][3];
    __shared__ int lin_s[64];
    __shared__ short H_lds[64 * HSTRIDE];
    __shared__ float red_s[64][4];

    const int t = threadIdx.x;
    const int wave = t >> 6, lane = t & 63, quad = lane >> 4, ln16 = lane & 15;
    const int qbase = blockIdx.x * 64;
    const int b = qbase >> 13;            // Q = 8192

    if (t < 64) {
        int g = qbase + t;
        float cy = coord[g * 2 + 0], cx = coord[g * 2 + 1];
        float ey = cell[g * 2 + 0], ex = cell[g * 2 + 1];
        float coy = cy - ey * 0.5f, cox = cx - ex * 0.5f;
        float cqy = fminf(fmaxf(coy + 1e-6f, -0.999999f), 0.999999f);
        float cqx = fminf(fmaxf(cox + 1e-6f, -0.999999f), 0.999999f);
        float fy = ((cqy + 1.0f) * 64.0f - 1.0f) * 0.5f;
        float fx = ((cqx + 1.0f) * 64.0f - 1.0f) * 0.5f;
        int iy = (int)rintf(fy); iy = min(max(iy, 0), 63);
        int ix = (int)rintf(fx); ix = min(max(ix, 0), 63);
        float qy = (float)iy * (1.0f / 32.0f) - 1.0f;
        float qx = (float)ix * (1.0f / 32.0f) - 1.0f;
        inp_s[t][0] = (coy - qy) * 32.0f;
        inp_s[t][1] = (cox - qx) * 32.0f;
        inp_s[t][2] = ey * 32.0f;
        lin_s[t] = iy * 64 + ix;
    }
    __syncthreads();

    // H1 column t
    {
        float w10 = w1[t], w11 = w1[256 + t], w12 = w1[512 + t], bb = b1[t];
#pragma unroll 8
        for (int m = 0; m < 64; ++m) {
            float v = fmaf(inp_s[m][0], w10, fmaf(inp_s[m][1], w11, fmaf(inp_s[m][2], w12, bb)));
            H_lds[m * HSTRIDE + t] = f2bf(fmaxf(v, 0.f));
        }
    }
    __syncthreads();

    // H2 = relu(H1 @ w2 + b2), MFMA, per-wave 64-col slice (4 subtiles)
    f32x4 acc[4][4];
#pragma unroll
    for (int a = 0; a < 4; ++a)
#pragma unroll
        for (int i = 0; i < 4; ++i) acc[a][i] = (f32x4){0.f, 0.f, 0.f, 0.f};
#pragma unroll
    for (int s = 0; s < 8; ++s) {
        short8 af[4];
#pragma unroll
        for (int ms = 0; ms < 4; ++ms)
            af[ms] = *(const short8*)(&H_lds[(ms * 16 + ln16) * HSTRIDE + s * 32 + quad * 8]);
#pragma unroll
        for (int i = 0; i < 4; ++i) {
            int n = (wave + 4 * i) * 16 + ln16;
            short8 bf = *(const short8*)(w2bT + n * 256 + s * 32 + quad * 8);
#pragma unroll
            for (int ms = 0; ms < 4; ++ms)
                acc[ms][i] = __builtin_amdgcn_mfma_f32_16x16x32_bf16(af[ms], bf, acc[ms][i], 0, 0, 0);
        }
    }
    __syncthreads();   // all H1 reads done, reuse buffer for H2
#pragma unroll
    for (int i = 0; i < 4; ++i) {
        int n = (wave + 4 * i) * 16 + ln16;
        float bb = b2v[n];
#pragma unroll
        for (int ms = 0; ms < 4; ++ms)
#pragma unroll
            for (int r = 0; r < 4; ++r) {
                int m = ms * 16 + quad * 4 + r;
                H_lds[m * HSTRIDE + n] = f2bf(fmaxf(acc[ms][i][r] + bb, 0.f));
            }
    }
    __syncthreads();

    // combine: wave w handles h-range [w*64, w*64+64) for all 64 queries
    {
        int m = lane;
        const short* Fr = F + (((long)(b * 4096 + lin_s[m])) * FROW);
        int h0 = wave * 64;
        float sum = 0.f;
#pragma unroll
        for (int i = 0; i < 8; ++i) {
            short8 fv = *(const short8*)(Fr + h0 + i * 8);
            short8 hv = *(const short8*)(&H_lds[m * HSTRIDE + h0 + i * 8]);
#pragma unroll
            for (int j = 0; j < 8; ++j)
                sum = fmaf(bf2f(fv[j]), bf2f(hv[j]), sum);
        }
        if (wave == 0) sum += bf2f(Fr[256]);
        red_s[m][wave] = sum;
    }
    __syncthreads();
    if (t < 64)
        out[qbase + t] = red_s[t][0] + red_s[t][1] + red_s[t][2] + red_s[t][3];
}

// ---------------------------------------------------------------------------
extern "C" void kernel_launch(void* const* d_in, const int* in_sizes, int n_in,
                              void* d_out, int out_size, void* d_ws, size_t ws_size,
                              hipStream_t stream) {
    const float* feat  = (const float*)d_in[0];
    const float* coord = (const float*)d_in[1];
    const float* cell  = (const float*)d_in[2];
    const float* w1    = (const float*)d_in[3];
    const float* b1    = (const float*)d_in[4];
    const float* w2    = (const float*)d_in[5];
    const float* b2    = (const float*)d_in[6];
    const float* w3    = (const float*)d_in[7];
    const float* b3    = (const float*)d_in[8];
    float* out = (float*)d_out;

    char* ws = (char*)d_ws;
    // workspace layout (16B-aligned offsets)
    short* w3cT  = (short*)(ws);                       // 272*576*2      = 313,344
    short* w2bT  = (short*)(ws + 313344);              // 256*256*2      = 131,072
    short* featT = (short*)(ws + 444416);              // 16*66*66*64*2  = 8,921,088
    short* F     = (short*)(ws + 9365504);             // 16*4096*264*2  = 34,603,008
    (void)ws_size; (void)in_sizes; (void)n_in; (void)out_size;

    prep_k<<<612, 256, 0, stream>>>(w2, w3, b3, w3cT, w2bT);
    transpose_k<<<BB * HT, 256, 0, stream>>>(feat, featT);
    conv_k<<<BB * HH, 256, 0, stream>>>(featT, w3cT, F);
    mlp_k<<<(BB * QQ) / 64, 256, 0, stream>>>(coord, cell, w1, b1, b2, w2bT, F, out);
}

// Round 3
// 197.648 us; speedup vs baseline: 2.9929x; 2.9929x over previous
//
#include <hip/hip_runtime.h>
#include <hip/hip_bf16.h>

// Problem constants
#define BB 16
#define CC 64
#define HH 64
#define WW 64
#define QQ 8192
#define HID 256
#define KK 576            // C*9
#define HT 66             // H + 2 halo
#define FROW 264          // 257 channels padded to 264 (16B-aligned rows)

typedef short short8 __attribute__((ext_vector_type(8)));
typedef float f32x4 __attribute__((ext_vector_type(4)));

__device__ __forceinline__ short f2bf(float f) {
    union { float f; unsigned u; } v; v.f = f;
    unsigned r = v.u + 0x7fffu + ((v.u >> 16) & 1u);
    return (short)(r >> 16);
}
__device__ __forceinline__ float bf2f(short s) {
    union { unsigned u; float f; } v; v.u = ((unsigned)(unsigned short)s) << 16;
    return v.f;
}

// ---------------------------------------------------------------------------
// Kernel P: repack weights to bf16.
//   w3convT[n][kk], kk = pos*64 + c :  = w3[n][c*9+pos] (n<256), b3[c*9+pos] (n==256), 0 pad
//   w2bT[n][k] = w2[k][n]
// ---------------------------------------------------------------------------
__global__ __launch_bounds__(256) void prep_k(const float* __restrict__ w2,
                                              const float* __restrict__ w3,
                                              const float* __restrict__ b3,
                                              short* __restrict__ w3cT,
                                              short* __restrict__ w2bT) {
    int stride = gridDim.x * blockDim.x;
    for (int idx = blockIdx.x * blockDim.x + threadIdx.x; idx < 272 * KK; idx += stride) {
        int n = idx / KK, kk = idx - n * KK;
        int pos = kk >> 6, c = kk & 63;
        float v = 0.f;
        if (n < 256)      v = w3[n * KK + c * 9 + pos];
        else if (n == 256) v = b3[c * 9 + pos];
        w3cT[idx] = f2bf(v);
    }
    for (int idx = blockIdx.x * blockDim.x + threadIdx.x; idx < 256 * 256; idx += stride) {
        int n = idx >> 8, k = idx & 255;
        w2bT[idx] = f2bf(w2[k * 256 + n]);
    }
}

// ---------------------------------------------------------------------------
// Kernel T: feat [b][c][y][x] f32  ->  featT [b][yy][xx][c] bf16 with zero halo
// ---------------------------------------------------------------------------
__global__ __launch_bounds__(256) void transpose_k(const float* __restrict__ feat,
                                                   short* __restrict__ featT) {
    __shared__ float ftile[64][65];
    const int t = threadIdx.x;
    const int b = blockIdx.x / HT;
    const int yy = blockIdx.x - b * HT;
    short* out_row = featT + ((b * HT + yy) * HT) * 64;   // plane of HT*64 shorts

    if (yy == 0 || yy == HT - 1) {
        for (int idx = t; idx < HT * 64; idx += 256) out_row[idx] = 0;
        return;
    }
    const int y = yy - 1;
    const float* src = feat + ((b * CC) * HH + y) * WW;   // + c*HH*WW + x
#pragma unroll
    for (int i = 0; i < 16; ++i) {
        int idx = i * 256 + t;
        int c = idx >> 6, x = idx & 63;
        ftile[c][x] = src[c * (HH * WW) + x];
    }
    // halo columns (xx=0 and xx=65)
    if (t < 64) out_row[t] = 0;
    else if (t < 128) out_row[(HT - 1) * 64 + (t - 64)] = 0;
    __syncthreads();
#pragma unroll
    for (int i = 0; i < 16; ++i) {
        int idx = i * 256 + t;
        int x = idx >> 6, c = idx & 63;
        out_row[(x + 1) * 64 + c] = f2bf(ftile[c][x]);
    }
}

// ---------------------------------------------------------------------------
// Kernel C: conv as implicit GEMM.  F[b,y,x,n] = sum_k A[pixel,k]*w3convT[n,k]
//   wg = (b,y): M=64 pixels, N=272, K=576.
//   ALL loop bounds are compile-time (5 subtiles for every wave; subtile 16 is
//   computed redundantly by waves 1..3 and only stored by wave 0) so that
//   acc[][] / bfr[][] stay in registers — runtime `nsub` in R1/R2 forced them
//   into scratch (HBM) and cost ~2.4 GB/dispatch of scratch traffic.
// ---------------------------------------------------------------------------
#define ALDS_STRIDE 72   // 64 kk + 8 pad (144B rows, 16B-aligned)
__global__ __launch_bounds__(256) void conv_k(const short* __restrict__ featT,
                                              const short* __restrict__ w3cT,
                                              short* __restrict__ F) {
    // union: first 64*72 shorts = A-tile during k-loop; whole = 64x264 C-tile in epilogue
    __shared__ short lds[64 * FROW];     // 33,792 B
    short* A_lds = lds;
    const int t = threadIdx.x;
    const int wave = t >> 6, lane = t & 63, quad = lane >> 4, ln16 = lane & 15;
    const int b = blockIdx.x >> 6, y = blockIdx.x & 63;

    f32x4 acc[4][5];
#pragma unroll
    for (int a = 0; a < 4; ++a)
#pragma unroll
        for (int i = 0; i < 5; ++i) acc[a][i] = (f32x4){0.f, 0.f, 0.f, 0.f};

    const short* featb = featT + b * (HT * HT * 64);

    for (int pos = 0; pos < 9; ++pos) {
        const int di = pos / 3;
        const int dj = pos - di * 3;
        const short* srcbase = featb + ((y + di) * HT + dj) * 64;  // + m*64 + c

        // Preload B fragments (global/L2; latency overlaps A-staging below).
        short8 bfr[2][5];
#pragma unroll
        for (int ks = 0; ks < 2; ++ks)
#pragma unroll
            for (int i = 0; i < 5; ++i) {
                int sub = (i < 4) ? (wave + 4 * i) : 16;
                int n = sub * 16 + ln16;
                bfr[ks][i] = *(const short8*)(w3cT + n * KK + pos * 64 + ks * 32 + quad * 8);
            }

        __syncthreads();   // previous iteration's A-frag reads complete
#pragma unroll
        for (int i = 0; i < 2; ++i) {
            int idx = i * 256 + t;          // 0..511 -> 64 rows x 8 segs
            int m = idx >> 3;
            int cs = (idx & 7) * 8;
            short8 v = *(const short8*)(srcbase + m * 64 + cs);
            *(short8*)(&A_lds[m * ALDS_STRIDE + cs]) = v;
        }
        __syncthreads();

#pragma unroll
        for (int ks = 0; ks < 2; ++ks) {
            short8 af[4];
#pragma unroll
            for (int ms = 0; ms < 4; ++ms)
                af[ms] = *(const short8*)(&A_lds[(ms * 16 + ln16) * ALDS_STRIDE + ks * 32 + quad * 8]);
#pragma unroll
            for (int i = 0; i < 5; ++i) {
#pragma unroll
                for (int ms = 0; ms < 4; ++ms)
                    acc[ms][i] = __builtin_amdgcn_mfma_f32_16x16x32_bf16(af[ms], bfr[ks][i], acc[ms][i], 0, 0, 0);
            }
        }
    }

    __syncthreads();   // all A-tile reads done; reuse lds as C-tile
    // Scatter accumulator into C_lds[x][n]  (compile-time indices throughout)
#pragma unroll
    for (int i = 0; i < 5; ++i) {
        int sub = (i < 4) ? (wave + 4 * i) : 16;
        int n = sub * 16 + ln16;
        bool store = (i < 4) || (wave == 0 && n < FROW);
        if (store) {
#pragma unroll
            for (int ms = 0; ms < 4; ++ms)
#pragma unroll
                for (int r = 0; r < 4; ++r) {
                    int x = ms * 16 + quad * 4 + r;
                    lds[x * FROW + n] = f2bf(acc[ms][i][r]);
                }
        }
    }
    __syncthreads();
    // Flat vectorized copy: LDS C-tile -> F (full-line coalesced stores)
    short8* dst = (short8*)(F + (long)(b * 64 + y) * 64 * FROW);
    const short8* src8 = (const short8*)lds;
    for (int idx = t; idx < (64 * FROW) / 8; idx += 256)
        dst[idx] = src8[idx];
}

// ---------------------------------------------------------------------------
// Kernel M: per-64-query tile: coords -> inp -> H1 (VALU) -> H2 (MFMA) ->
//           dot with gathered F row.
// ---------------------------------------------------------------------------
#define HSTRIDE 264
__global__ __launch_bounds__(256) void mlp_k(const float* __restrict__ coord,
                                             const float* __restrict__ cell,
                                             const float* __restrict__ w1,
                                             const float* __restrict__ b1,
                                             const float* __restrict__ b2v,
                                             const short* __restrict__ w2bT,
                                             const short* __restrict__ F,
                                             float* __restrict__ out) {
    __shared__ float inp_s[64][3];
    __shared__ int lin_s[64];
    __shared__ short H_lds[64 * HSTRIDE];
    __shared__ float red_s[64][4];

    const int t = threadIdx.x;
    const int wave = t >> 6, lane = t & 63, quad = lane >> 4, ln16 = lane & 15;
    const int qbase = blockIdx.x * 64;
    const int b = qbase >> 13;            // Q = 8192

    if (t < 64) {
        int g = qbase + t;
        float cy = coord[g * 2 + 0], cx = coord[g * 2 + 1];
        float ey = cell[g * 2 + 0], ex = cell[g * 2 + 1];
        float coy = cy - ey * 0.5f, cox = cx - ex * 0.5f;
        float cqy = fminf(fmaxf(coy + 1e-6f, -0.999999f), 0.999999f);
        float cqx = fminf(fmaxf(cox + 1e-6f, -0.999999f), 0.999999f);
        float fy = ((cqy + 1.0f) * 64.0f - 1.0f) * 0.5f;
        float fx = ((cqx + 1.0f) * 64.0f - 1.0f) * 0.5f;
        int iy = (int)rintf(fy); iy = min(max(iy, 0), 63);
        int ix = (int)rintf(fx); ix = min(max(ix, 0), 63);
        float qy = (float)iy * (1.0f / 32.0f) - 1.0f;
        float qx = (float)ix * (1.0f / 32.0f) - 1.0f;
        inp_s[t][0] = (coy - qy) * 32.0f;
        inp_s[t][1] = (cox - qx) * 32.0f;
        inp_s[t][2] = ey * 32.0f;
        lin_s[t] = iy * 64 + ix;
    }
    __syncthreads();

    // H1 column t
    {
        float w10 = w1[t], w11 = w1[256 + t], w12 = w1[512 + t], bb = b1[t];
#pragma unroll 8
        for (int m = 0; m < 64; ++m) {
            float v = fmaf(inp_s[m][0], w10, fmaf(inp_s[m][1], w11, fmaf(inp_s[m][2], w12, bb)));
            H_lds[m * HSTRIDE + t] = f2bf(fmaxf(v, 0.f));
        }
    }
    __syncthreads();

    // H2 = relu(H1 @ w2 + b2), MFMA, per-wave 64-col slice (4 subtiles)
    f32x4 acc[4][4];
#pragma unroll
    for (int a = 0; a < 4; ++a)
#pragma unroll
        for (int i = 0; i < 4; ++i) acc[a][i] = (f32x4){0.f, 0.f, 0.f, 0.f};
#pragma unroll
    for (int s = 0; s < 8; ++s) {
        short8 af[4];
#pragma unroll
        for (int ms = 0; ms < 4; ++ms)
            af[ms] = *(const short8*)(&H_lds[(ms * 16 + ln16) * HSTRIDE + s * 32 + quad * 8]);
#pragma unroll
        for (int i = 0; i < 4; ++i) {
            int n = (wave + 4 * i) * 16 + ln16;
            short8 bf = *(const short8*)(w2bT + n * 256 + s * 32 + quad * 8);
#pragma unroll
            for (int ms = 0; ms < 4; ++ms)
                acc[ms][i] = __builtin_amdgcn_mfma_f32_16x16x32_bf16(af[ms], bf, acc[ms][i], 0, 0, 0);
        }
    }
    __syncthreads();   // all H1 reads done, reuse buffer for H2
#pragma unroll
    for (int i = 0; i < 4; ++i) {
        int n = (wave + 4 * i) * 16 + ln16;
        float bb = b2v[n];
#pragma unroll
        for (int ms = 0; ms < 4; ++ms)
#pragma unroll
            for (int r = 0; r < 4; ++r) {
                int m = ms * 16 + quad * 4 + r;
                H_lds[m * HSTRIDE + n] = f2bf(fmaxf(acc[ms][i][r] + bb, 0.f));
            }
    }
    __syncthreads();

    // combine: wave w handles h-range [w*64, w*64+64) for all 64 queries
    {
        int m = lane;
        const short* Fr = F + (((long)(b * 4096 + lin_s[m])) * FROW);
        int h0 = wave * 64;
        float sum = 0.f;
#pragma unroll
        for (int i = 0; i < 8; ++i) {
            short8 fv = *(const short8*)(Fr + h0 + i * 8);
            short8 hv = *(const short8*)(&H_lds[m * HSTRIDE + h0 + i * 8]);
#pragma unroll
            for (int j = 0; j < 8; ++j)
                sum = fmaf(bf2f(fv[j]), bf2f(hv[j]), sum);
        }
        if (wave == 0) sum += bf2f(Fr[256]);
        red_s[m][wave] = sum;
    }
    __syncthreads();
    if (t < 64)
        out[qbase + t] = red_s[t][0] + red_s[t][1] + red_s[t][2] + red_s[t][3];
}

// ---------------------------------------------------------------------------
extern "C" void kernel_launch(void* const* d_in, const int* in_sizes, int n_in,
                              void* d_out, int out_size, void* d_ws, size_t ws_size,
                              hipStream_t stream) {
    const float* feat  = (const float*)d_in[0];
    const float* coord = (const float*)d_in[1];
    const float* cell  = (const float*)d_in[2];
    const float* w1    = (const float*)d_in[3];
    const float* b1    = (const float*)d_in[4];
    const float* w2    = (const float*)d_in[5];
    const float* b2    = (const float*)d_in[6];
    const float* w3    = (const float*)d_in[7];
    const float* b3    = (const float*)d_in[8];
    float* out = (float*)d_out;

    char* ws = (char*)d_ws;
    // workspace layout (16B-aligned offsets)
    short* w3cT  = (short*)(ws);                       // 272*576*2      = 313,344
    short* w2bT  = (short*)(ws + 313344);              // 256*256*2      = 131,072
    short* featT = (short*)(ws + 444416);              // 16*66*66*64*2  = 8,921,088
    short* F     = (short*)(ws + 9365504);             // 16*4096*264*2  = 34,603,008
    (void)ws_size; (void)in_sizes; (void)n_in; (void)out_size;

    prep_k<<<612, 256, 0, stream>>>(w2, w3, b3, w3cT, w2bT);
    transpose_k<<<BB * HT, 256, 0, stream>>>(feat, featT);
    conv_k<<<BB * HH, 256, 0, stream>>>(featT, w3cT, F);
    mlp_k<<<(BB * QQ) / 64, 256, 0, stream>>>(coord, cell, w1, b1, b2, w2bT, F, out);
}

// Round 4
// 188.396 us; speedup vs baseline: 3.1399x; 1.0491x over previous
//
#include <hip/hip_runtime.h>
#include <hip/hip_bf16.h>

// Problem constants
#define BB 16
#define CC 64
#define HH 64
#define WW 64
#define QQ 8192
#define HID 256
#define KK 576            // C*9
#define HT 66             // H + 2 halo
#define FROW 264          // 257 channels padded to 264 (16B-aligned rows)

typedef short short8 __attribute__((ext_vector_type(8)));
typedef short sv4    __attribute__((ext_vector_type(4)));
typedef float f32x4  __attribute__((ext_vector_type(4)));

__device__ __forceinline__ short f2bf(float f) {
    union { float f; unsigned u; } v; v.f = f;
    unsigned r = v.u + 0x7fffu + ((v.u >> 16) & 1u);
    return (short)(r >> 16);
}
__device__ __forceinline__ float bf2f(short s) {
    union { unsigned u; float f; } v; v.u = ((unsigned)(unsigned short)s) << 16;
    return v.f;
}
// Barrier that only drains LDS (lgkmcnt) — does NOT force vmcnt(0), so global
// prefetches issued before it stay in flight. Safe when the barrier only
// protects LDS data (all our mlp_k barriers).
__device__ __forceinline__ void barrier_lds() {
    asm volatile("s_waitcnt lgkmcnt(0)" ::: "memory");
    __builtin_amdgcn_s_barrier();
    asm volatile("" ::: "memory");
}

// ---------------------------------------------------------------------------
// Kernel P: repack weights to bf16.
//   w3convT[n][kk], kk = pos*64 + c :  = w3[n][c*9+pos] (n<256), b3[c*9+pos] (n==256), 0 pad
//   w2bT[n][k] = w2[k][n]
// ---------------------------------------------------------------------------
__global__ __launch_bounds__(256) void prep_k(const float* __restrict__ w2,
                                              const float* __restrict__ w3,
                                              const float* __restrict__ b3,
                                              short* __restrict__ w3cT,
                                              short* __restrict__ w2bT) {
    int stride = gridDim.x * blockDim.x;
    for (int idx = blockIdx.x * blockDim.x + threadIdx.x; idx < 272 * KK; idx += stride) {
        int n = idx / KK, kk = idx - n * KK;
        int pos = kk >> 6, c = kk & 63;
        float v = 0.f;
        if (n < 256)      v = w3[n * KK + c * 9 + pos];
        else if (n == 256) v = b3[c * 9 + pos];
        w3cT[idx] = f2bf(v);
    }
    for (int idx = blockIdx.x * blockDim.x + threadIdx.x; idx < 256 * 256; idx += stride) {
        int n = idx >> 8, k = idx & 255;
        w2bT[idx] = f2bf(w2[k * 256 + n]);
    }
}

// ---------------------------------------------------------------------------
// Kernel T: feat [b][c][y][x] f32  ->  featT [b][yy][xx][c] bf16 with zero halo
// ---------------------------------------------------------------------------
__global__ __launch_bounds__(256) void transpose_k(const float* __restrict__ feat,
                                                   short* __restrict__ featT) {
    __shared__ float ftile[64][65];
    const int t = threadIdx.x;
    const int b = blockIdx.x / HT;
    const int yy = blockIdx.x - b * HT;
    short* out_row = featT + ((b * HT + yy) * HT) * 64;   // plane of HT*64 shorts

    if (yy == 0 || yy == HT - 1) {
        for (int idx = t; idx < HT * 64; idx += 256) out_row[idx] = 0;
        return;
    }
    const int y = yy - 1;
    const float* src = feat + ((b * CC) * HH + y) * WW;   // + c*HH*WW + x
#pragma unroll
    for (int i = 0; i < 16; ++i) {
        int idx = i * 256 + t;
        int c = idx >> 6, x = idx & 63;
        ftile[c][x] = src[c * (HH * WW) + x];
    }
    // halo columns (xx=0 and xx=65)
    if (t < 64) out_row[t] = 0;
    else if (t < 128) out_row[(HT - 1) * 64 + (t - 64)] = 0;
    __syncthreads();
#pragma unroll
    for (int i = 0; i < 16; ++i) {
        int idx = i * 256 + t;
        int x = idx >> 6, c = idx & 63;
        out_row[(x + 1) * 64 + c] = f2bf(ftile[c][x]);
    }
}

// ---------------------------------------------------------------------------
// Kernel C: conv as implicit GEMM.  F[b,y,x,n] = sum_k A[pixel,k]*w3convT[n,k]
//   wg = (b,y): M=64 pixels, N=272, K=576.
//   v2: the 9 per-pos A-tiles are shifted views of one 3x66x64 slab -> stage
//   the slab ONCE (row stride 68 shorts for bank spread; b64 fragment reads),
//   then run the whole 18-step K-loop with ZERO barriers (was 18/wg).
// ---------------------------------------------------------------------------
#define SLAB_STRIDE 68   // 64 ch + 4 pad; 136 B rows (8B-aligned -> ds b64)
__global__ __launch_bounds__(256) void conv_k(const short* __restrict__ featT,
                                              const short* __restrict__ w3cT,
                                              short* __restrict__ F) {
    // union: slab (3*66*68 = 13464 shorts) during K-loop; 64x264 C-tile in epilogue
    __shared__ short lds[64 * FROW];     // 33,792 B
    const int t = threadIdx.x;
    const int wave = t >> 6, lane = t & 63, quad = lane >> 4, ln16 = lane & 15;
    const int b = blockIdx.x >> 6, y = blockIdx.x & 63;

    f32x4 acc[4][5];
#pragma unroll
    for (int a = 0; a < 4; ++a)
#pragma unroll
        for (int i = 0; i < 5; ++i) acc[a][i] = (f32x4){0.f, 0.f, 0.f, 0.f};

    // Stage slab: featT rows y..y+2 are contiguous (3*66*64 = 12672 shorts)
    const short* slabsrc = featT + b * (HT * HT * 64) + y * (HT * 64);
#pragma unroll
    for (int it = 0; it < 7; ++it) {
        int i = it * 256 + t;             // chunk of 8 shorts; never straddles a row
        if (i < 1584) {
            short8 v = *(const short8*)(slabsrc + i * 8);
            int row = i >> 3, cs = (i & 7) * 8;
            short* d = &lds[row * SLAB_STRIDE + cs];
            *(sv4*)d       = __builtin_shufflevector(v, v, 0, 1, 2, 3);
            *(sv4*)(d + 4) = __builtin_shufflevector(v, v, 4, 5, 6, 7);
        }
    }
    __syncthreads();

#pragma unroll
    for (int pos = 0; pos < 9; ++pos) {
        const int di = pos / 3, dj = pos - di * 3;
#pragma unroll
        for (int ks = 0; ks < 2; ++ks) {
            short8 bfr[5];
#pragma unroll
            for (int i = 0; i < 5; ++i) {
                int sub = (i < 4) ? (wave + 4 * i) : 16;
                int n = sub * 16 + ln16;
                bfr[i] = *(const short8*)(w3cT + n * KK + pos * 64 + ks * 32 + quad * 8);
            }
            short8 af[4];
#pragma unroll
            for (int ms = 0; ms < 4; ++ms) {
                const short* ap = &lds[(di * 66 + ms * 16 + ln16 + dj) * SLAB_STRIDE + ks * 32 + quad * 8];
                sv4 a0 = *(const sv4*)ap;
                sv4 a1 = *(const sv4*)(ap + 4);
                af[ms] = __builtin_shufflevector(a0, a1, 0, 1, 2, 3, 4, 5, 6, 7);
            }
#pragma unroll
            for (int i = 0; i < 5; ++i)
#pragma unroll
                for (int ms = 0; ms < 4; ++ms)
                    acc[ms][i] = __builtin_amdgcn_mfma_f32_16x16x32_bf16(af[ms], bfr[i], acc[ms][i], 0, 0, 0);
        }
    }

    __syncthreads();   // slab reads done; reuse lds as C-tile
#pragma unroll
    for (int i = 0; i < 5; ++i) {
        int sub = (i < 4) ? (wave + 4 * i) : 16;
        int n = sub * 16 + ln16;
        bool store = (i < 4) || (wave == 0 && n < FROW);
        if (store) {
#pragma unroll
            for (int ms = 0; ms < 4; ++ms)
#pragma unroll
                for (int r = 0; r < 4; ++r) {
                    int x = ms * 16 + quad * 4 + r;
                    lds[x * FROW + n] = f2bf(acc[ms][i][r]);
                }
        }
    }
    __syncthreads();
    short8* dst = (short8*)(F + (long)(b * 64 + y) * 64 * FROW);
    const short8* src8 = (const short8*)lds;
    for (int idx = t; idx < (64 * FROW) / 8; idx += 256)
        dst[idx] = src8[idx];
}

// ---------------------------------------------------------------------------
// Kernel M v2: transposed-H2 structure, register combine, vmem-transparent
// barriers. Per wg: 64 queries, 4 waves; wave w owns n-range [w*64, w*64+64).
//   - every lane computes coords for query qbase+lane -> lin/inp in regs
//   - F fragments prefetched at start (short4, C-layout-matching), stay in
//     flight through H1 because barriers don't drain vmcnt
//   - H2^T = mfma(w2_nfrag, h1_mfrag): D[row=n][col=m] -> combine is pure
//     register math + 2 shuffles; no epilogue LDS round-trip
// ---------------------------------------------------------------------------
#define HSTRIDE 264
__global__ __launch_bounds__(256) void mlp_k(const float* __restrict__ coord,
                                             const float* __restrict__ cell,
                                             const float* __restrict__ w1,
                                             const float* __restrict__ b1,
                                             const float* __restrict__ b2v,
                                             const short* __restrict__ w2bT,
                                             const short* __restrict__ F,
                                             float* __restrict__ out) {
    __shared__ float inp_s[64][3];
    __shared__ short H_lds[64 * HSTRIDE];
    __shared__ float red_s[64][4];

    const int t = threadIdx.x;
    const int wave = t >> 6, lane = t & 63, quad = lane >> 4, ln16 = lane & 15;
    const int qbase = blockIdx.x * 64;
    const int b = qbase >> 13;            // Q = 8192

    // --- coords: every wave computes all 64 queries (lane = query) ---
    const int g = qbase + lane;
    const float2 cc = *(const float2*)(coord + g * 2);
    const float2 ce = *(const float2*)(cell + g * 2);
    const float coy = cc.x - ce.x * 0.5f, cox = cc.y - ce.y * 0.5f;
    const float cqy = fminf(fmaxf(coy + 1e-6f, -0.999999f), 0.999999f);
    const float cqx = fminf(fmaxf(cox + 1e-6f, -0.999999f), 0.999999f);
    int iy = (int)rintf(((cqy + 1.0f) * 64.0f - 1.0f) * 0.5f); iy = min(max(iy, 0), 63);
    int ix = (int)rintf(((cqx + 1.0f) * 64.0f - 1.0f) * 0.5f); ix = min(max(ix, 0), 63);
    const int lin = iy * 64 + ix;
    const float in0 = (coy - ((float)iy * (1.0f / 32.0f) - 1.0f)) * 32.0f;
    const float in1 = (cox - ((float)ix * (1.0f / 32.0f) - 1.0f)) * 32.0f;
    const float in2 = ce.x * 32.0f;

    // --- F prefetch: fv[ms][i] = F[lin[ms*16+ln16]][wave*64 + i*16 + quad*4 .. +3]
    const short* Fb = F + (long)b * 4096 * FROW;
    sv4 fv[4][4];
#pragma unroll
    for (int ms = 0; ms < 4; ++ms) {
        int linm = __shfl(lin, ms * 16 + ln16, 64);
        const short* Fr = Fb + (long)linm * FROW + wave * 64 + quad * 4;
#pragma unroll
        for (int i = 0; i < 4; ++i) fv[ms][i] = *(const sv4*)(Fr + i * 16);
    }
    const short fb = Fb[(long)lin * FROW + 256];   // b3 column (used by wave 0)

    if (t < 64) { inp_s[t][0] = in0; inp_s[t][1] = in1; inp_s[t][2] = in2; }
    barrier_lds();

    // --- H1: thread t computes hidden column t for all 64 queries ---
    {
        float w10 = w1[t], w11 = w1[256 + t], w12 = w1[512 + t], bb = b1[t];
#pragma unroll 8
        for (int m = 0; m < 64; ++m) {
            float v = fmaf(inp_s[m][0], w10, fmaf(inp_s[m][1], w11, fmaf(inp_s[m][2], w12, bb)));
            H_lds[m * HSTRIDE + t] = f2bf(fmaxf(v, 0.f));
        }
    }
    barrier_lds();

    // --- H2^T: acc2[i][ms] = D[row = n-subtile i][col = m-subtile ms] ---
    f32x4 acc2[4][4];
#pragma unroll
    for (int i = 0; i < 4; ++i)
#pragma unroll
        for (int ms = 0; ms < 4; ++ms) acc2[i][ms] = (f32x4){0.f, 0.f, 0.f, 0.f};
#pragma unroll
    for (int s = 0; s < 8; ++s) {
        short8 wf[4];
#pragma unroll
        for (int i = 0; i < 4; ++i) {
            int n = wave * 64 + i * 16 + ln16;
            wf[i] = *(const short8*)(w2bT + n * 256 + s * 32 + quad * 8);
        }
        short8 hf[4];
#pragma unroll
        for (int ms = 0; ms < 4; ++ms)
            hf[ms] = *(const short8*)(&H_lds[(ms * 16 + ln16) * HSTRIDE + s * 32 + quad * 8]);
#pragma unroll
        for (int i = 0; i < 4; ++i)
#pragma unroll
            for (int ms = 0; ms < 4; ++ms)
                acc2[i][ms] = __builtin_amdgcn_mfma_f32_16x16x32_bf16(wf[i], hf[ms], acc2[i][ms], 0, 0, 0);
    }

    // --- combine in registers: pred[m] += relu(H2+b2)[n] * F[lin[m]][n] ---
    float part[4] = {0.f, 0.f, 0.f, 0.f};
#pragma unroll
    for (int i = 0; i < 4; ++i) {
        f32x4 b2q = *(const f32x4*)(b2v + wave * 64 + i * 16 + quad * 4);
#pragma unroll
        for (int ms = 0; ms < 4; ++ms)
#pragma unroll
            for (int r = 0; r < 4; ++r)
                part[ms] = fmaf(fmaxf(acc2[i][ms][r] + b2q[r], 0.f), bf2f(fv[ms][i][r]), part[ms]);
    }
#pragma unroll
    for (int ms = 0; ms < 4; ++ms) {
        part[ms] += __shfl_xor(part[ms], 16, 64);
        part[ms] += __shfl_xor(part[ms], 32, 64);
    }
    if (quad == 0) {
#pragma unroll
        for (int ms = 0; ms < 4; ++ms) red_s[ms * 16 + ln16][wave] = part[ms];
    }
    barrier_lds();
    if (t < 64)
        out[qbase + t] = red_s[t][0] + red_s[t][1] + red_s[t][2] + red_s[t][3] + bf2f(fb);
}

// ---------------------------------------------------------------------------
extern "C" void kernel_launch(void* const* d_in, const int* in_sizes, int n_in,
                              void* d_out, int out_size, void* d_ws, size_t ws_size,
                              hipStream_t stream) {
    const float* feat  = (const float*)d_in[0];
    const float* coord = (const float*)d_in[1];
    const float* cell  = (const float*)d_in[2];
    const float* w1    = (const float*)d_in[3];
    const float* b1    = (const float*)d_in[4];
    const float* w2    = (const float*)d_in[5];
    const float* b2    = (const float*)d_in[6];
    const float* w3    = (const float*)d_in[7];
    const float* b3    = (const float*)d_in[8];
    float* out = (float*)d_out;

    char* ws = (char*)d_ws;
    // workspace layout (16B-aligned offsets)
    short* w3cT  = (short*)(ws);                       // 272*576*2      = 313,344
    short* w2bT  = (short*)(ws + 313344);              // 256*256*2      = 131,072
    short* featT = (short*)(ws + 444416);              // 16*66*66*64*2  = 8,921,088
    short* F     = (short*)(ws + 9365504);             // 16*4096*264*2  = 34,603,008
    (void)ws_size; (void)in_sizes; (void)n_in; (void)out_size;

    prep_k<<<612, 256, 0, stream>>>(w2, w3, b3, w3cT, w2bT);
    transpose_k<<<BB * HT, 256, 0, stream>>>(feat, featT);
    conv_k<<<BB * HH, 256, 0, stream>>>(featT, w3cT, F);
    mlp_k<<<(BB * QQ) / 64, 256, 0, stream>>>(coord, cell, w1, b1, b2, w2bT, F, out);
}